// Round 1
// baseline (1038.256 us; speedup 1.0000x reference)
//
#include <hip/hip_runtime.h>

typedef _Float16 f16;
typedef _Float16 f16x8 __attribute__((ext_vector_type(8)));
typedef float f32x4 __attribute__((ext_vector_type(4)));

#define NB 32
#define NT 512
#define ND 256
#define NH 512
#define NK 8
#define M_REAL 16352   // NB*(NT-1)
#define M_PAD 16384
#define RDIM 768       // ND + NH

// output offsets (floats)
#define OFF_PI 0
#define OFF_S  256
#define OFF_H  1048832
#define OFF_Y  1179904
#define OFF_G1 1196288
#define OFF_G2 1327360
#define OFF_F  2373888
#define OFF_BW 2504960

// ws offsets (bytes)
#define WS_A    0            // f16 [16384][768] = 25165824 B
#define WS_B    25165824     // f16 [4096][768]  = 6291456 B
#define WS_BIAS 31457280     // f32 [4096]
#define WS_SQ   31473664     // f32 [16384][8][8] = 4194304 B
#define WS_NEED 35667968

#define CH_CONST 1887.3506062251f   // -0.5*512*(log(2pi)+log(1e-4))
#define CY_CONST 943.6753031126f    // -0.5*256*(...)
#define LOG2E 1.4426950408889634f
#define LN2 0.6931471805599453f

__device__ __forceinline__ float fexp2(float x) { return __builtin_amdgcn_exp2f(x); }
__device__ __forceinline__ float flog2(float x) { return __builtin_amdgcn_logf(x); }
__device__ __forceinline__ float ftanh(float x) {
    x = fminf(10.f, fmaxf(-10.f, x));
    float t = fexp2(x * 2.885390081777927f);  // 2*log2(e)
    return (t - 1.f) * __builtin_amdgcn_rcpf(t + 1.f);
}
__device__ __forceinline__ float lse8v(const float* z) {
    float M = fmaxf(fmaxf(fmaxf(z[0], z[1]), fmaxf(z[2], z[3])),
                    fmaxf(fmaxf(z[4], z[5]), fmaxf(z[6], z[7])));
    float s = 0.f;
#pragma unroll
    for (int j = 0; j < 8; ++j) s += fexp2((z[j] - M) * LOG2E);
    return M + LN2 * flog2(s);
}

// ---------------- conversion kernels ----------------
__global__ void conv_a_kernel(const float* __restrict__ x, const float* __restrict__ h,
                              f16* __restrict__ A) {
    const int m = blockIdx.x;
    const int tid = threadIdx.x;
    if (m >= M_REAL) {
        for (int c = tid; c < RDIM; c += 256) A[(size_t)m * RDIM + c] = (f16)0.f;
        return;
    }
    const int b = m / 511;
    const int t = m - b * 511;
    const float* xs = x + (size_t)(b * NT + t + 1) * ND;
    const float* hs = h + (size_t)(b * NT + t) * NH;
    for (int c = tid; c < RDIM; c += 256) {
        float v = (c < ND) ? xs[c] : hs[c - ND];
        A[(size_t)m * RDIM + c] = (f16)v;
    }
}

__global__ void conv_b_kernel(const float* __restrict__ Wih, const float* __restrict__ Whh,
                              const float* __restrict__ bih, const float* __restrict__ bhh,
                              f16* __restrict__ Bm, float* __restrict__ biasc) {
    const int n = blockIdx.x;  // n = k*512 + g, matches flattened (K,H)
    const int tid = threadIdx.x;
    for (int c = tid; c < RDIM; c += 256) {
        float v = (c < ND) ? Wih[(size_t)n * ND + c] : Whh[(size_t)n * NH + (c - ND)];
        Bm[(size_t)n * RDIM + c] = (f16)v;
    }
    if (tid == 0) biasc[n] = bih[n] + bhh[n];
}

// ---------------- big GEMM + tanh + sq-reduce epilogue ----------------
// C[m][n] = sum_r A[m][r]*Bm[n][r];  pre = C + bias[n]; x_out = tanh(pre)
// sq_part[m][k][slot] = sum over this wave's 64 columns of (tgt - x_out)^2
__global__ __launch_bounds__(256) void gemm_kernel(const f16* __restrict__ A,
                                                   const f16* __restrict__ Bm,
                                                   const float* __restrict__ biasc,
                                                   const float* __restrict__ sampled_h,
                                                   float* __restrict__ sq_part) {
    // LDS layout: [chunk(8 f16 = 16B)][row 0..127][8]
    __shared__ __align__(16) f16 Ash[8 * 128 * 8];
    __shared__ __align__(16) f16 Bsh[8 * 128 * 8];
    const int tid = threadIdx.x;
    const int lane = tid & 63;
    const int wave = tid >> 6;
    const int wx = wave & 1, wy = wave >> 1;
    const int tn = blockIdx.x & 31, tm = blockIdx.x >> 5;
    const int m0 = tm * 128, n0 = tn * 128;
    const int q = lane >> 4, l15 = lane & 15;

    f32x4 acc[4][4];
#pragma unroll
    for (int a = 0; a < 4; ++a)
#pragma unroll
        for (int b = 0; b < 4; ++b) acc[a][b] = (f32x4)0.f;

    for (int kk = 0; kk < RDIM; kk += 64) {
        __syncthreads();
#pragma unroll
        for (int inst = 0; inst < 4; ++inst) {
            const int fb = inst * 256 + wave * 64;  // wave-uniform
            const int f = fb + lane;
            const int ch = f >> 7, row = f & 127;
            const f16* ga = A + (size_t)(m0 + row) * RDIM + kk + ch * 8;
            const f16* gb = Bm + (size_t)(n0 + row) * RDIM + kk + ch * 8;
            __builtin_amdgcn_global_load_lds(
                (const __attribute__((address_space(1))) void*)ga,
                (__attribute__((address_space(3))) void*)&Ash[fb * 8], 16, 0, 0);
            __builtin_amdgcn_global_load_lds(
                (const __attribute__((address_space(1))) void*)gb,
                (__attribute__((address_space(3))) void*)&Bsh[fb * 8], 16, 0, 0);
        }
        __syncthreads();
#pragma unroll
        for (int ks = 0; ks < 2; ++ks) {
            const int cb = ks * 4 + q;
            f16x8 af[4], bfr[4];
#pragma unroll
            for (int mi = 0; mi < 4; ++mi)
                af[mi] = *(const f16x8*)&Ash[(cb * 128 + wy * 64 + mi * 16 + l15) * 8];
#pragma unroll
            for (int ni = 0; ni < 4; ++ni)
                bfr[ni] = *(const f16x8*)&Bsh[(cb * 128 + wx * 64 + ni * 16 + l15) * 8];
#pragma unroll
            for (int mi = 0; mi < 4; ++mi)
#pragma unroll
                for (int ni = 0; ni < 4; ++ni)
                    acc[mi][ni] = __builtin_amdgcn_mfma_f32_16x16x32_f16(af[mi], bfr[ni],
                                                                         acc[mi][ni], 0, 0, 0);
        }
    }

    // epilogue: C/D layout col=lane&15, row=(lane>>4)*4+reg
    const int nbase = n0 + wx * 64;
    const int k0 = n0 >> 9;
    const int slot = (nbase & 511) >> 6;
#pragma unroll
    for (int mi = 0; mi < 4; ++mi) {
#pragma unroll
        for (int r = 0; r < 4; ++r) {
            const int mg = m0 + wy * 64 + mi * 16 + q * 4 + r;  // uniform across shfl group
            if (mg < M_REAL) {
                const int bb = mg / 511;
                const int tt = mg - bb * 511;
                const float* tgt = sampled_h + (size_t)((bb << 9) + tt + 1) * NH;
                float rs = 0.f;
#pragma unroll
                for (int ni = 0; ni < 4; ++ni) {
                    const int ng = nbase + ni * 16 + l15;
                    const float pre = acc[mi][ni][r] + biasc[ng];
                    const float v = ftanh(pre);
                    const float d = tgt[ng & 511] - v;
                    rs += d * d;
                }
                rs += __shfl_xor(rs, 1, 64);
                rs += __shfl_xor(rs, 2, 64);
                rs += __shfl_xor(rs, 4, 64);
                rs += __shfl_xor(rs, 8, 64);
                if (l15 == 0) sq_part[(size_t)(mg * 8 + k0) * 8 + slot] = rs;
            }
        }
    }
}

__global__ void finalize_h_kernel(const float* __restrict__ sq_part, float* __restrict__ Ph) {
    const int g = blockIdx.x * 256 + threadIdx.x;  // < 131072 = B*T*K
    const int b = g >> 12;
    const int t = (g >> 3) & 511;
    const int k = g & 7;
    float val;
    if (t == 0) {
        val = CH_CONST;
    } else {
        const int m = b * 511 + (t - 1);
        const float4* p = (const float4*)&sq_part[(size_t)(m * 8 + k) * 8];
        const float4 a = p[0], c = p[1];
        const float s = a.x + a.y + a.z + a.w + c.x + c.y + c.z + c.w;
        val = CH_CONST - 5000.f * s;  // 0.5/VAR = 5000
    }
    Ph[g] = val;
}

// ---------------- trans = tanh(h_prev @ Wt^T + bt), column log-softmax ----------------
__global__ __launch_bounds__(64) void trans_kernel(const float* __restrict__ h,
                                                   const float* __restrict__ Wt,
                                                   const float* __restrict__ btv,
                                                   float* __restrict__ Ps) {
    __shared__ float hsh[8][512];
    const int lane = threadIdx.x;
    const int mbase = blockIdx.x * 8;
#pragma unroll
    for (int r = 0; r < 8; ++r) {
        const int m = mbase + r;
        const int b = m / 511, t = m - b * 511;
        const float4* src = (const float4*)(h + (size_t)(b * NT + t) * NH);
        ((float4*)hsh[r])[lane] = src[lane];
        ((float4*)hsh[r])[lane + 64] = src[lane + 64];
    }
    __syncthreads();
    const int c = lane;  // output index = i*8 + j
    float acc[8];
#pragma unroll
    for (int r = 0; r < 8; ++r) acc[r] = btv[c];
    const float4* w4 = (const float4*)(Wt + (size_t)c * NH);
    for (int hh = 0; hh < 128; ++hh) {
        const float4 w = w4[hh];
#pragma unroll
        for (int r = 0; r < 8; ++r) {
            const float4 hv = ((const float4*)hsh[r])[hh];
            acc[r] += w.x * hv.x + w.y * hv.y + w.z * hv.z + w.w * hv.w;
        }
    }
#pragma unroll
    for (int r = 0; r < 8; ++r) {
        const float tr = ftanh(acc[r]);
        // lse over i (lanes c ^ {8,16,32})
        float M = tr;
        M = fmaxf(M, __shfl_xor(M, 8, 64));
        M = fmaxf(M, __shfl_xor(M, 16, 64));
        M = fmaxf(M, __shfl_xor(M, 32, 64));
        float s = fexp2((tr - M) * LOG2E);
        s += __shfl_xor(s, 8, 64);
        s += __shfl_xor(s, 16, 64);
        s += __shfl_xor(s, 32, 64);
        const float lse = M + LN2 * flog2(s);
        const int m = mbase + r;
        const int b = m / 511, t = m - b * 511;
        Ps[(size_t)(b * NT + t + 1) * 64 + c] = tr - lse;
    }
}

__global__ void s0_kernel(float* __restrict__ out) {
    const int g = blockIdx.x * 256 + threadIdx.x;  // < 2048
    const int b = g >> 6, c = g & 63;
    out[OFF_S + (size_t)b * NT * 64 + c] = ((c >> 3) == (c & 7)) ? 1.f : 0.f;
}

// ---------------- emission MLP + gaussian lp ----------------
__global__ __launch_bounds__(256) void emission_kernel(
    const float* __restrict__ h, const float* __restrict__ y, const float* __restrict__ W1,
    const float* __restrict__ b1, const float* __restrict__ W2, const float* __restrict__ b2,
    const float* __restrict__ W3, const float* __restrict__ b3, float* __restrict__ Py) {
    __shared__ float ssh[512];
    __shared__ float h1sh[32];
    __shared__ float h2sh[64];
    __shared__ float red[256];
    const int pos = blockIdx.x;
    const int tid = threadIdx.x;
    {
        const float2 v = ((const float2*)(h + (size_t)pos * NH))[tid];
        ssh[tid * 2] = v.x;
        ssh[tid * 2 + 1] = v.y;
    }
    __syncthreads();
    const int o = tid >> 3, seg = tid & 7;
    const float4* w4 = (const float4*)(W1 + (size_t)o * NH + seg * 64);
    const float4* s4 = (const float4*)(ssh + seg * 64);
    float p = 0.f;
#pragma unroll
    for (int it = 0; it < 16; ++it) {
        const int idx = (it + seg * 2) & 15;  // stagger to dodge bank conflicts
        const float4 w = w4[idx], sv = s4[idx];
        p += w.x * sv.x + w.y * sv.y + w.z * sv.z + w.w * sv.w;
    }
    red[tid] = p;
    __syncthreads();
    if (tid < 32) {
        float s = b1[tid];
#pragma unroll
        for (int j = 0; j < 8; ++j) s += red[tid * 8 + j];
        h1sh[tid] = fmaxf(s, 0.f);
    }
    __syncthreads();
    if (tid < 64) {
        float s = b2[tid];
#pragma unroll
        for (int j = 0; j < 32; ++j) s += W2[tid * 32 + j] * h1sh[j];
        h2sh[tid] = fmaxf(s, 0.f);
    }
    __syncthreads();
    float s = b3[tid];
    const float4* w34 = (const float4*)(W3 + (size_t)tid * 64);
    const float4* h24 = (const float4*)h2sh;
#pragma unroll
    for (int j = 0; j < 16; ++j) {
        const float4 w = w34[j], hv = h24[j];
        s += w.x * hv.x + w.y * hv.y + w.z * hv.z + w.w * hv.w;
    }
    const float d = y[(size_t)pos * ND + tid] - s;
    float sq = d * d;
#pragma unroll
    for (int off = 32; off > 0; off >>= 1) sq += __shfl_xor(sq, off, 64);
    if ((tid & 63) == 0) red[tid >> 6] = sq;
    __syncthreads();
    if (tid == 0) Py[pos] = CY_CONST - 5000.f * (red[0] + red[1] + red[2] + red[3]);
}

__global__ void pinit_kernel(const float* __restrict__ initials, float* __restrict__ out) {
    const int tid = threadIdx.x;  // 256
    float z[8];
#pragma unroll
    for (int j = 0; j < 8; ++j) z[j] = initials[j];
    const float l = lse8v(z);
    out[OFF_PI + tid] = z[tid & 7] - l;
}

// ---------------- forward / backward scans (2 blocks) ----------------
__global__ __launch_bounds__(256) void scan_kernel(const float* __restrict__ initials,
                                                   float* __restrict__ out) {
    const float* Ps = out + OFF_S;
    const float* Ph = out + OFF_H;
    const float* Py = out + OFF_Y;
    __shared__ float ash[256];
    const int tid = threadIdx.x;
    const int b = tid >> 3, i = tid & 7;

    if (blockIdx.x == 0) {
        float z0[8];
#pragma unroll
        for (int j = 0; j < 8; ++j) z0[j] = initials[j];
        const float linit = lse8v(z0);
        float* Fw = out + OFF_F;
        float a = (z0[i] - linit) + CH_CONST + Py[b * NT];
        Fw[(size_t)(b * NT) * 8 + i] = a;
        ash[tid] = a;
        __syncthreads();
        // prefetch t=1
        size_t base = ((size_t)(b * NT + 1) * 8 + i) * 8;
        float4 sA = *(const float4*)&Ps[base];
        float4 sB = *(const float4*)&Ps[base + 4];
        float eh = Ph[(size_t)(b * NT + 1) * 8 + i];
        float ey = Py[b * NT + 1];
        for (int t = 1; t < NT; ++t) {
            const float4 cA = sA, cB = sB;
            const float ce = eh + ey;
            if (t + 1 < NT) {
                base = ((size_t)(b * NT + t + 1) * 8 + i) * 8;
                sA = *(const float4*)&Ps[base];
                sB = *(const float4*)&Ps[base + 4];
                eh = Ph[(size_t)(b * NT + t + 1) * 8 + i];
                ey = Py[b * NT + t + 1];
            }
            float z[8];
            z[0] = ash[b * 8 + 0] + cA.x;
            z[1] = ash[b * 8 + 1] + cA.y;
            z[2] = ash[b * 8 + 2] + cA.z;
            z[3] = ash[b * 8 + 3] + cA.w;
            z[4] = ash[b * 8 + 4] + cB.x;
            z[5] = ash[b * 8 + 5] + cB.y;
            z[6] = ash[b * 8 + 6] + cB.z;
            z[7] = ash[b * 8 + 7] + cB.w;
            const float an = ce + lse8v(z);
            __syncthreads();
            ash[tid] = an;
            Fw[(size_t)(b * NT + t) * 8 + i] = an;
            __syncthreads();
        }
    } else {
        float* Bw = out + OFF_BW;
        Bw[(size_t)(b * NT + NT - 1) * 8 + i] = 0.f;
        ash[tid] = 0.f;
        __syncthreads();
        float sp[8];
        float4 ph0, ph1;
        float py;
        {
            const size_t t1 = (size_t)(b * NT + NT - 1);
#pragma unroll
            for (int ii = 0; ii < 8; ++ii) sp[ii] = Ps[(t1 * 8 + ii) * 8 + i];
            ph0 = ((const float4*)&Ph[t1 * 8])[0];
            ph1 = ((const float4*)&Ph[t1 * 8])[1];
            py = Py[t1];
        }
        for (int t = NT - 2; t >= 0; --t) {
            float cs[8];
#pragma unroll
            for (int ii = 0; ii < 8; ++ii) cs[ii] = sp[ii];
            const float4 cph0 = ph0, cph1 = ph1;
            const float cpy = py;
            if (t > 0) {
                const size_t t1 = (size_t)(b * NT + t);
#pragma unroll
                for (int ii = 0; ii < 8; ++ii) sp[ii] = Ps[(t1 * 8 + ii) * 8 + i];
                ph0 = ((const float4*)&Ph[t1 * 8])[0];
                ph1 = ((const float4*)&Ph[t1 * 8])[1];
                py = Py[t1];
            }
            float z[8];
            z[0] = cs[0] + cph0.x + ash[b * 8 + 0];
            z[1] = cs[1] + cph0.y + ash[b * 8 + 1];
            z[2] = cs[2] + cph0.z + ash[b * 8 + 2];
            z[3] = cs[3] + cph0.w + ash[b * 8 + 3];
            z[4] = cs[4] + cph1.x + ash[b * 8 + 4];
            z[5] = cs[5] + cph1.y + ash[b * 8 + 5];
            z[6] = cs[6] + cph1.z + ash[b * 8 + 6];
            z[7] = cs[7] + cph1.w + ash[b * 8 + 7];
            const float bn = lse8v(z) + cpy;
            __syncthreads();
            ash[tid] = bn;
            Bw[(size_t)(b * NT + t) * 8 + i] = bn;
            __syncthreads();
        }
    }
}

__global__ void gamma1_kernel(float* __restrict__ out) {
    const int pos = blockIdx.x * 256 + threadIdx.x;  // < 16384
    const float* Fw = out + OFF_F;
    const float* Bw = out + OFF_BW;
    const float4 fa = ((const float4*)&Fw[(size_t)pos * 8])[0];
    const float4 fb = ((const float4*)&Fw[(size_t)pos * 8])[1];
    const float4 ba = ((const float4*)&Bw[(size_t)pos * 8])[0];
    const float4 bb = ((const float4*)&Bw[(size_t)pos * 8])[1];
    float ab[8] = {fa.x + ba.x, fa.y + ba.y, fa.z + ba.z, fa.w + ba.w,
                   fb.x + bb.x, fb.y + bb.y, fb.z + bb.z, fb.w + bb.w};
    const float l = lse8v(ab);
    float* G1 = out + OFF_G1;
    float4 o0 = {ab[0] - l, ab[1] - l, ab[2] - l, ab[3] - l};
    float4 o1 = {ab[4] - l, ab[5] - l, ab[6] - l, ab[7] - l};
    ((float4*)&G1[(size_t)pos * 8])[0] = o0;
    ((float4*)&G1[(size_t)pos * 8])[1] = o1;
}

__global__ void gamma2_kernel(float* __restrict__ out) {
    const int gidx = blockIdx.x * 256 + threadIdx.x;  // < 130816 = 32*511*8
    const int pos = gidx >> 3;                        // b*511 + t
    const int i = gidx & 7;
    const int b = pos / 511, t = pos - b * 511;
    const float* Ps = out + OFF_S;
    const float* Ph = out + OFF_H;
    const float* Py = out + OFF_Y;
    const float* Fw = out + OFF_F;
    const float* Bw = out + OFF_BW;
    const size_t t1 = (size_t)(b * NT + t + 1);
    const float ei = Ph[t1 * 8 + i] + Py[t1] + Bw[t1 * 8 + i];
    const float4 sa = ((const float4*)&Ps[(t1 * 8 + i) * 8])[0];
    const float4 sb = ((const float4*)&Ps[(t1 * 8 + i) * 8])[1];
    const float4 fa = ((const float4*)&Fw[(size_t)(b * NT + t) * 8])[0];
    const float4 fb = ((const float4*)&Fw[(size_t)(b * NT + t) * 8])[1];
    float z[8] = {fa.x + sa.x + ei, fa.y + sa.y + ei, fa.z + sa.z + ei, fa.w + sa.w + ei,
                  fb.x + sb.x + ei, fb.y + sb.y + ei, fb.z + sb.z + ei, fb.w + sb.w + ei};
    float M = fmaxf(fmaxf(fmaxf(z[0], z[1]), fmaxf(z[2], z[3])),
                    fmaxf(fmaxf(z[4], z[5]), fmaxf(z[6], z[7])));
    M = fmaxf(M, __shfl_xor(M, 1, 64));
    M = fmaxf(M, __shfl_xor(M, 2, 64));
    M = fmaxf(M, __shfl_xor(M, 4, 64));
    float s = 0.f;
#pragma unroll
    for (int j = 0; j < 8; ++j) s += fexp2((z[j] - M) * LOG2E);
    s += __shfl_xor(s, 1, 64);
    s += __shfl_xor(s, 2, 64);
    s += __shfl_xor(s, 4, 64);
    const float l = M + LN2 * flog2(s);
    float* G2 = out + OFF_G2;
    float4 o0 = {z[0] - l, z[1] - l, z[2] - l, z[3] - l};
    float4 o1 = {z[4] - l, z[5] - l, z[6] - l, z[7] - l};
    ((float4*)&G2[(size_t)gidx * 8])[0] = o0;
    ((float4*)&G2[(size_t)gidx * 8])[1] = o1;
}

extern "C" void kernel_launch(void* const* d_in, const int* in_sizes, int n_in, void* d_out,
                              int out_size, void* d_ws, size_t ws_size, hipStream_t stream) {
    const float* x = (const float*)d_in[0];
    const float* y = (const float*)d_in[1];
    const float* h = (const float*)d_in[2];
    const float* initials = (const float*)d_in[3];
    const float* Wih = (const float*)d_in[4];
    const float* Whh = (const float*)d_in[5];
    const float* bih = (const float*)d_in[6];
    const float* bhh = (const float*)d_in[7];
    const float* Wt = (const float*)d_in[8];
    const float* btv = (const float*)d_in[9];
    const float* W1 = (const float*)d_in[10];
    const float* b1 = (const float*)d_in[11];
    const float* W2 = (const float*)d_in[12];
    const float* b2 = (const float*)d_in[13];
    const float* W3 = (const float*)d_in[14];
    const float* b3 = (const float*)d_in[15];
    float* out = (float*)d_out;
    char* ws = (char*)d_ws;
    if (ws_size < (size_t)WS_NEED) return;  // scratch too small; fail loudly via poison
    f16* Aws = (f16*)(ws + WS_A);
    f16* Bws = (f16*)(ws + WS_B);
    float* biasc = (float*)(ws + WS_BIAS);
    float* sqp = (float*)(ws + WS_SQ);

    conv_a_kernel<<<M_PAD, 256, 0, stream>>>(x, h, Aws);
    conv_b_kernel<<<4096, 256, 0, stream>>>(Wih, Whh, bih, bhh, Bws, biasc);
    gemm_kernel<<<4096, 256, 0, stream>>>(Aws, Bws, biasc, h, sqp);
    finalize_h_kernel<<<512, 256, 0, stream>>>(sqp, out + OFF_H);
    trans_kernel<<<2044, 64, 0, stream>>>(h, Wt, btv, out + OFF_S);
    s0_kernel<<<8, 256, 0, stream>>>(out);
    emission_kernel<<<NB * NT, 256, 0, stream>>>(h, y, W1, b1, W2, b2, W3, b3, out + OFF_Y);
    pinit_kernel<<<1, 256, 0, stream>>>(initials, out);
    scan_kernel<<<2, 256, 0, stream>>>(initials, out);
    gamma1_kernel<<<64, 256, 0, stream>>>(out);
    gamma2_kernel<<<511, 256, 0, stream>>>(out);
}